// Round 5
// baseline (920.880 us; speedup 1.0000x reference)
//
#include <hip/hip_runtime.h>
#include <stdint.h>

#define NPTS 2048
#define SOUT 512
#define NB   2
#define T2   64

typedef float vf2 __attribute__((ext_vector_type(2)));

// ---- DPP wave64 max-reduce (nonneg values; bound_ctrl zero-fill is safe) ----
__device__ __forceinline__ float wave_allmax_f32(float v) {
    int x = __float_as_int(v); int t;
    t = __builtin_amdgcn_update_dpp(x, x, 0x111, 0xF, 0xF, true); v = fmaxf(v, __int_as_float(t)); x = __float_as_int(v);
    t = __builtin_amdgcn_update_dpp(x, x, 0x112, 0xF, 0xF, true); v = fmaxf(v, __int_as_float(t)); x = __float_as_int(v);
    t = __builtin_amdgcn_update_dpp(x, x, 0x114, 0xF, 0xF, true); v = fmaxf(v, __int_as_float(t)); x = __float_as_int(v);
    t = __builtin_amdgcn_update_dpp(x, x, 0x118, 0xF, 0xF, true); v = fmaxf(v, __int_as_float(t)); x = __float_as_int(v);
    t = __builtin_amdgcn_update_dpp(x, x, 0x142, 0xA, 0xF, true); v = fmaxf(v, __int_as_float(t)); x = __float_as_int(v);
    t = __builtin_amdgcn_update_dpp(x, x, 0x143, 0xC, 0xF, true); v = fmaxf(v, __int_as_float(t)); x = __float_as_int(v);
    return __int_as_float(__builtin_amdgcn_readlane(x, 63));
}

// ---------------- Kernel 1: FPS, single wave per batch, zero barriers --------
// Lane owns 32 consecutive points (k-major: idx = lane*32+k). The whole
// argmax is in-wave: packed-f32 distance update (IEEE-rn, contract off ->
// bit-exact vs numpy), contiguous-segment (val,idx) tree (left-if->= on
// contiguous halves == first-occurrence ties), DPP value max + ballot/ctz
// (lowest lane == lowest global index), readlane for the winner's local k.
__global__ __launch_bounds__(T2, 1) void fps_kernel(const float* __restrict__ xyz,
                                                    float* __restrict__ new_xyz,
                                                    int far0, int far1) {
    __shared__ float4 sxyz[NPTS];          // 32 KB (centroid gather)
    __shared__ float  scf[SOUT * 3];       // result staging, written once at end
    const int b    = blockIdx.x;
    const int lane = threadIdx.x;
    const float* xb = xyz + (size_t)b * NPTS * 3;
    for (int i = lane; i < NPTS; i += T2)
        sxyz[i] = make_float4(xb[i*3+0], xb[i*3+1], xb[i*3+2], 0.0f);
    __syncthreads();                       // 1 wave: cheap

    vf2 PX[16], PY[16], PZ[16], DD[16];
    const int gbase = lane * 32;
#pragma unroll
    for (int j = 0; j < 16; ++j) {
        float4 p0 = sxyz[gbase + 2*j + 0];
        float4 p1 = sxyz[gbase + 2*j + 1];
        PX[j].x = p0.x; PX[j].y = p1.x;
        PY[j].x = p0.y; PY[j].y = p1.y;
        PZ[j].x = p0.z; PZ[j].y = p1.z;
        DD[j].x = 1e10f; DD[j].y = 1e10f;
    }
    const int far = (b == 0) ? far0 : far1;
    float4 c0 = sxyz[far];
    float cx = c0.x, cy = c0.y, cz = c0.z;

    for (int s = 0; s < SOUT; ++s) {
        if (lane == 0) { scf[s*3+0] = cx; scf[s*3+1] = cy; scf[s*3+2] = cz; }
        if (s == SOUT - 1) break;
        // packed distance update: each op separately rounded (contract off)
        {
#pragma clang fp contract(off)
            vf2 vcx; vcx.x = cx; vcx.y = cx;
            vf2 vcy; vcy.x = cy; vcy.y = cy;
            vf2 vcz; vcz.x = cz; vcz.y = cz;
#pragma unroll
            for (int j = 0; j < 16; ++j) {
                vf2 dx = PX[j] - vcx;
                vf2 dy = PY[j] - vcy;
                vf2 dz = PZ[j] - vcz;
                vf2 d2 = (dx*dx + dy*dy) + dz*dz;   // ((xx+yy)+zz), rn each
                DD[j].x = fminf(DD[j].x, d2.x);
                DD[j].y = fminf(DD[j].y, d2.y);
            }
        }
        // per-lane argmax over DD[0..31] (first occurrence) via contiguous tree
        float v16[16]; int i16[16];
#pragma unroll
        for (int j = 0; j < 16; ++j) {
            bool l = DD[j].x >= DD[j].y;
            v16[j] = l ? DD[j].x : DD[j].y;
            i16[j] = l ? (2*j) : (2*j + 1);
        }
        float v8[8]; int i8[8];
#pragma unroll
        for (int j = 0; j < 8; ++j) {
            bool l = v16[2*j] >= v16[2*j+1];
            v8[j] = l ? v16[2*j] : v16[2*j+1];
            i8[j] = l ? i16[2*j] : i16[2*j+1];
        }
        float v4[4]; int i4[4];
#pragma unroll
        for (int j = 0; j < 4; ++j) {
            bool l = v8[2*j] >= v8[2*j+1];
            v4[j] = l ? v8[2*j] : v8[2*j+1];
            i4[j] = l ? i8[2*j] : i8[2*j+1];
        }
        float v2[2]; int i2[2];
#pragma unroll
        for (int j = 0; j < 2; ++j) {
            bool l = v4[2*j] >= v4[2*j+1];
            v2[j] = l ? v4[2*j] : v4[2*j+1];
            i2[j] = l ? i4[2*j] : i4[2*j+1];
        }
        bool lf = v2[0] >= v2[1];
        float bv = lf ? v2[0] : v2[1];
        int   bk = lf ? i2[0] : i2[1];
        // wave winner
        float wmax = wave_allmax_f32(bv);
        unsigned long long msk = __ballot(bv == wmax);
        int l0 = (int)__builtin_ctzll(msk);
        int k0 = __builtin_amdgcn_readlane(bk, l0);
        float4 cc = sxyz[l0 * 32 + k0];    // uniform LDS read
        cx = cc.x; cy = cc.y; cz = cc.z;
    }
    __syncthreads();
    float* ob = new_xyz + (size_t)b * SOUT * 3;
    for (int i = lane; i < SOUT * 3; i += T2) ob[i] = scf[i];
}

// ---------------- Kernel 2: radius group + MLP(16->32->32->64) + maxpool -----
// One query per block, 2 waves. Both waves redundantly scan/compact (identical
// writes, no barrier); then wave w takes neighbor chunks tb = w*64, step 128.
// L1/L2: lane = neighbor. L3: LDS transpose (per-wave region) -> lane = output
// channel, row loop capped at the chunk's valid rows. Final 2-way max merge.
__global__ __launch_bounds__(128, 1) void group_mlp_kernel(
        const float* __restrict__ xyz,  const float* __restrict__ points,
        const float* __restrict__ w1,   const float* __restrict__ b1,
        const float* __restrict__ w2,   const float* __restrict__ b2,
        const float* __restrict__ w3,   const float* __restrict__ b3,
        const float* __restrict__ new_xyz, float* __restrict__ new_points) {
    __shared__ float sw1[32*16];
    __shared__ float sw2[32*32];
    __shared__ float sb1[32], sb2[32];
    __shared__ unsigned short sidx[NPTS];  // 4 KB
    __shared__ float sh2[2][64*36];        // 18 KB, per-wave, stride 36
    __shared__ float smx[2][64];
    const int tid  = threadIdx.x;
    const int lane = tid & 63;
    const int w    = tid >> 6;
    for (int i = tid; i <  512; i += 128) sw1[i] = w1[i];
    for (int i = tid; i < 1024; i += 128) sw2[i] = w2[i];
    if (tid < 32) sb1[tid] = b1[tid];
    else if (tid < 64) sb2[tid - 32] = b2[tid - 32];

    float wf3[32];                         // lane's w3 row (lane = out channel)
    {
        const float4* w3v = (const float4*)(w3 + lane * 32);
#pragma unroll
        for (int j = 0; j < 8; ++j) {
            float4 v = w3v[j];
            wf3[j*4+0] = v.x; wf3[j*4+1] = v.y; wf3[j*4+2] = v.z; wf3[j*4+3] = v.w;
        }
    }
    const float rb3 = b3[lane];

    const int q = blockIdx.x;
    const int b = q >> 9;
    const int s = q & (SOUT - 1);
    const float qx = new_xyz[q*3+0], qy = new_xyz[q*3+1], qz = new_xyz[q*3+2];
    const float qs = __fadd_rn(__fadd_rn(__fmul_rn(qx,qx), __fmul_rn(qy,qy)), __fmul_rn(qz,qz));
    const float* xb = xyz    + (size_t)b * NPTS * 3;
    const float* pb = points + (size_t)b * 13 * NPTS;
    __syncthreads();                       // weights staged by both waves

    // redundant per-wave scan: identical deterministic result in both waves
    int cnt = 0;
    for (int r = 0; r < NPTS / T2; ++r) {
        int n = r * T2 + lane;
        float x = xb[n*3+0], y = xb[n*3+1], z = xb[n*3+2];
        float pn = __fadd_rn(__fadd_rn(__fmul_rn(x,x), __fmul_rn(y,y)), __fmul_rn(z,z));
        float dt = __fadd_rn(__fadd_rn(__fmul_rn(qx,x), __fmul_rn(qy,y)), __fmul_rn(qz,z));
        float sqr = __fsub_rn(__fadd_rn(qs, pn), __fmul_rn(2.0f, dt));
        bool sel = !(sqr > 0.04f);
        unsigned long long m = __ballot(sel);
        if (sel) sidx[cnt + __popcll(m & ((1ull << lane) - 1ull))] = (unsigned short)n;
        cnt += (int)__popcll(m);
    }
    const int K = cnt;                     // >= 1
    const int nfirst = (int)sidx[0];       // own-wave write, in-order LDS

    float mx = -3.0e38f;
    for (int tb = w * T2; tb < K; tb += 2 * T2) {
        int m = tb + lane;
        int n = (m < K) ? (int)sidx[m] : nfirst;
        float f[16];
        f[0] = xb[n*3+0] - qx;
        f[1] = xb[n*3+1] - qy;
        f[2] = xb[n*3+2] - qz;
#pragma unroll
        for (int c = 0; c < 13; ++c) f[3+c] = pb[c*NPTS + n];
        float h1[32];
#pragma unroll
        for (int o = 0; o < 32; ++o) {
            float acc = sb1[o];
            const float4* wr = (const float4*)(sw1 + o*16);
#pragma unroll
            for (int c4 = 0; c4 < 4; ++c4) {
                float4 wv = wr[c4];
                acc = fmaf(f[c4*4+0], wv.x, acc);
                acc = fmaf(f[c4*4+1], wv.y, acc);
                acc = fmaf(f[c4*4+2], wv.z, acc);
                acc = fmaf(f[c4*4+3], wv.w, acc);
            }
            h1[o] = fmaxf(acc, 0.0f);
        }
        float h2[32];
#pragma unroll
        for (int o = 0; o < 32; ++o) {
            float acc = sb2[o];
            const float4* wr = (const float4*)(sw2 + o*32);
#pragma unroll
            for (int c4 = 0; c4 < 8; ++c4) {
                float4 wv = wr[c4];
                acc = fmaf(h1[c4*4+0], wv.x, acc);
                acc = fmaf(h1[c4*4+1], wv.y, acc);
                acc = fmaf(h1[c4*4+2], wv.z, acc);
                acc = fmaf(h1[c4*4+3], wv.w, acc);
            }
            h2[o] = fmaxf(acc, 0.0f);
        }
        // stage h2 into this wave's region (lane = row), then lane = channel
        {
            float4* row = (float4*)(sh2[w] + lane * 36);
#pragma unroll
            for (int c4 = 0; c4 < 8; ++c4)
                row[c4] = make_float4(h2[c4*4+0], h2[c4*4+1], h2[c4*4+2], h2[c4*4+3]);
        }
        int rows = K - tb; if (rows > T2) rows = T2;   // cap at valid rows
#pragma unroll 4
        for (int n2 = 0; n2 < rows; ++n2) {
            const float4* hr = (const float4*)(sh2[w] + n2 * 36);
            float acc = rb3;
#pragma unroll
            for (int c4 = 0; c4 < 8; ++c4) {
                float4 h = hr[c4];
                acc = fmaf(h.x, wf3[c4*4+0], acc);
                acc = fmaf(h.y, wf3[c4*4+1], acc);
                acc = fmaf(h.z, wf3[c4*4+2], acc);
                acc = fmaf(h.w, wf3[c4*4+3], acc);
            }
            mx = fmaxf(mx, acc);
        }
        // same-wave LDS ordering: no barrier needed before next chunk
    }
    smx[w][lane] = mx;
    __syncthreads();
    if (tid < T2) {
        float v = fmaxf(smx[0][tid], smx[1][tid]);
        new_points[((size_t)b * 64 + tid) * SOUT + s] = v;   // (B, 64, S)
    }
}

// ---------------- host: threefry2x32 (JAX key(42) randint seed) --------------
static inline uint32_t rotl32(uint32_t x, int r) { return (x << r) | (x >> (32 - r)); }
static void threefry2x32_host(uint32_t k0, uint32_t k1, uint32_t& x0, uint32_t& x1) {
    const int R[2][4] = {{13,15,26,6},{17,29,16,24}};
    uint32_t ks[3] = {k0, k1, k0 ^ k1 ^ 0x1BD11BDAu};
    x0 += ks[0]; x1 += ks[1];
    for (int i = 0; i < 5; ++i) {
        for (int j = 0; j < 4; ++j) { x0 += x1; x1 = rotl32(x1, R[i & 1][j]); x1 ^= x0; }
        x0 += ks[(i + 1) % 3];
        x1 += ks[(i + 2) % 3] + (uint32_t)(i + 1);
    }
}

extern "C" void kernel_launch(void* const* d_in, const int* in_sizes, int n_in,
                              void* d_out, int out_size, void* d_ws, size_t ws_size,
                              hipStream_t stream) {
    const float* xyz    = (const float*)d_in[0];
    const float* points = (const float*)d_in[1];
    const float* w1 = (const float*)d_in[2];
    const float* b1 = (const float*)d_in[3];
    const float* w2 = (const float*)d_in[4];
    const float* b2 = (const float*)d_in[5];
    const float* w3 = (const float*)d_in[6];
    const float* b3 = (const float*)d_in[7];
    float* out        = (float*)d_out;
    float* new_xyz    = out;                      // (B, S, 3)
    float* new_points = out + NB * SOUT * 3;      // (B, 64, S)

    // jax.random.randint(key(42), (2,), 0, 2048), modern JAX
    // (jax_threefry_partitionable=True): _randint splits the key first:
    //   k1, k2 = split(key); result = random_bits(k2, 32, (2,)) & 2047
    // foldlike split: k2 = threefry((0,42),(0,1)) full pair.
    // partitionable bits: elem i = xor-halves of threefry(k2, (0,i)).
    // (VERIFIED passing in rounds 3-4 — do not change.)
    uint32_t k2a = 0, k2b = 1; threefry2x32_host(0u, 42u, k2a, k2b);
    uint32_t u0 = 0, u1 = 0;  threefry2x32_host(k2a, k2b, u0, u1);
    uint32_t v0 = 0, v1 = 1;  threefry2x32_host(k2a, k2b, v0, v1);
    int far0 = (int)((u0 ^ u1) & (NPTS - 1));
    int far1 = (int)((v0 ^ v1) & (NPTS - 1));

    hipLaunchKernelGGL(fps_kernel, dim3(NB), dim3(T2), 0, stream,
                       xyz, new_xyz, far0, far1);
    hipLaunchKernelGGL(group_mlp_kernel, dim3(NB * SOUT), dim3(128), 0, stream,
                       xyz, points, w1, b1, w2, b2, w3, b3, new_xyz, new_points);
}

// Round 6
// 400.146 us; speedup vs baseline: 2.3014x; 2.3014x over previous
//
#include <hip/hip_runtime.h>
#include <stdint.h>

#define NPTS 2048
#define SOUT 512
#define NB   2
#define T1   256
#define PPT  (NPTS / T1)   // 8 points per thread, k-major
#define NW   (T1 / 64)     // 4 waves
#define T2   64

typedef float vf2 __attribute__((ext_vector_type(2)));

// ---- DPP wave64 max-reduce (nonneg values; bound_ctrl zero-fill is safe) ----
__device__ __forceinline__ float wave_allmax_f32(float v) {
    int x = __float_as_int(v); int t;
    t = __builtin_amdgcn_update_dpp(x, x, 0x111, 0xF, 0xF, true); v = fmaxf(v, __int_as_float(t)); x = __float_as_int(v);
    t = __builtin_amdgcn_update_dpp(x, x, 0x112, 0xF, 0xF, true); v = fmaxf(v, __int_as_float(t)); x = __float_as_int(v);
    t = __builtin_amdgcn_update_dpp(x, x, 0x114, 0xF, 0xF, true); v = fmaxf(v, __int_as_float(t)); x = __float_as_int(v);
    t = __builtin_amdgcn_update_dpp(x, x, 0x118, 0xF, 0xF, true); v = fmaxf(v, __int_as_float(t)); x = __float_as_int(v);
    t = __builtin_amdgcn_update_dpp(x, x, 0x142, 0xA, 0xF, true); v = fmaxf(v, __int_as_float(t)); x = __float_as_int(v);
    t = __builtin_amdgcn_update_dpp(x, x, 0x143, 0xC, 0xF, true); v = fmaxf(v, __int_as_float(t)); x = __float_as_int(v);
    return __int_as_float(__builtin_amdgcn_readlane(x, 63));
}
__device__ __forceinline__ float lane_bcast(float v, int l) {
    return __int_as_float(__builtin_amdgcn_readlane(__float_as_int(v), l));
}

// ---------------- Kernel 1: FPS, 4 waves, 8 pts/lane (R4 base + cuts) --------
// k-major: lane owns [tid*8, tid*8+8); wave w owns [512w, 512w+512) so cross-
// wave value ties resolve to the LOWER wave = lower global index (strict >
// ascending merge). Coords carried through the local tree + readlane -> no
// sxyz LDS reads inside the round loop. One barrier/round, parity slots.
__global__ __launch_bounds__(T1, 1) void fps_kernel(const float* __restrict__ xyz,
                                                    float* __restrict__ new_xyz,
                                                    int far0, int far1) {
    __shared__ float4 sxyz[NPTS];          // 32 KB (init + far only)
    __shared__ float4 slot[2][NW];         // {val, x, y, z}, parity-buffered
    __shared__ float  scf[SOUT * 3];
    const int b    = blockIdx.x;
    const int tid  = threadIdx.x;
    const int lane = tid & 63;
    const int wv   = tid >> 6;
    const float* xb = xyz + (size_t)b * NPTS * 3;
    for (int i = tid; i < NPTS; i += T1)
        sxyz[i] = make_float4(xb[i*3+0], xb[i*3+1], xb[i*3+2], 0.0f);
    __syncthreads();

    vf2 PX[4], PY[4], PZ[4], DD[4];
    const int gbase = tid * PPT;
#pragma unroll
    for (int j = 0; j < 4; ++j) {
        float4 p0 = sxyz[gbase + 2*j + 0];
        float4 p1 = sxyz[gbase + 2*j + 1];
        PX[j].x = p0.x; PX[j].y = p1.x;
        PY[j].x = p0.y; PY[j].y = p1.y;
        PZ[j].x = p0.z; PZ[j].y = p1.z;
        DD[j].x = 1e10f; DD[j].y = 1e10f;
    }
    const int far = (b == 0) ? far0 : far1;
    float4 c0 = sxyz[far];
    float cx = c0.x, cy = c0.y, cz = c0.z;

    for (int s = 0; s < SOUT; ++s) {
        if (tid == 0) { scf[s*3+0] = cx; scf[s*3+1] = cy; scf[s*3+2] = cz; }
        if (s == SOUT - 1) break;
        // packed distance update (each op separately rounded: contract off ->
        // bit-exact vs numpy; validated in round 5)
        {
#pragma clang fp contract(off)
            vf2 vcx; vcx.x = cx; vcx.y = cx;
            vf2 vcy; vcy.x = cy; vcy.y = cy;
            vf2 vcz; vcz.x = cz; vcz.y = cz;
#pragma unroll
            for (int j = 0; j < 4; ++j) {
                vf2 dx = PX[j] - vcx;
                vf2 dy = PY[j] - vcy;
                vf2 dz = PZ[j] - vcz;
                vf2 d2 = (dx*dx + dy*dy) + dz*dz;   // ((xx+yy)+zz), rn each
                DD[j].x = fminf(DD[j].x, d2.x);
                DD[j].y = fminf(DD[j].y, d2.y);
            }
        }
        // local argmax over 8 pts, coords carried; left-if->= on contiguous
        // halves == first-occurrence (lowest index) tie-break
        float v1[4], x1v[4], y1v[4], z1v[4];
#pragma unroll
        for (int j = 0; j < 4; ++j) {
            bool l = DD[j].x >= DD[j].y;
            v1[j]  = l ? DD[j].x : DD[j].y;
            x1v[j] = l ? PX[j].x : PX[j].y;
            y1v[j] = l ? PY[j].x : PY[j].y;
            z1v[j] = l ? PZ[j].x : PZ[j].y;
        }
        float v2v[2], x2v[2], y2v[2], z2v[2];
#pragma unroll
        for (int j = 0; j < 2; ++j) {
            bool l = v1[2*j] >= v1[2*j+1];
            v2v[j] = l ? v1[2*j]  : v1[2*j+1];
            x2v[j] = l ? x1v[2*j] : x1v[2*j+1];
            y2v[j] = l ? y1v[2*j] : y1v[2*j+1];
            z2v[j] = l ? z1v[2*j] : z1v[2*j+1];
        }
        bool lf = v2v[0] >= v2v[1];
        float bv = lf ? v2v[0] : v2v[1];
        float bx = lf ? x2v[0] : x2v[1];
        float by = lf ? y2v[0] : y2v[1];
        float bz = lf ? z2v[0] : z2v[1];
        // wave winner: DPP value max; lowest tie lane = lowest index (k-major)
        float wmax = wave_allmax_f32(bv);
        unsigned long long msk = __ballot(bv == wmax);
        int l0 = (int)__builtin_ctzll(msk);
        float wvia = lane_bcast(bx, l0);
        float wvib = lane_bcast(by, l0);
        float wvic = lane_bcast(bz, l0);
        const int par = s & 1;
        if (lane == 0) slot[par][wv] = make_float4(wmax, wvia, wvib, wvic);
        __syncthreads();
        float4 a0 = slot[par][0];
        float bvv = a0.x; cx = a0.y; cy = a0.z; cz = a0.w;
#pragma unroll
        for (int w = 1; w < NW; ++w) {
            float4 aw = slot[par][w];
            bool take = aw.x > bvv;                 // tie -> lower wave = lower idx
            bvv = take ? aw.x : bvv;
            cx  = take ? aw.y : cx;
            cy  = take ? aw.z : cy;
            cz  = take ? aw.w : cz;
        }
    }
    __syncthreads();
    float* ob = new_xyz + (size_t)b * SOUT * 3;
    for (int i = tid; i < SOUT * 3; i += T1) ob[i] = scf[i];
}

// ---------------- Kernel 2: radius group + MLP(16->32->32->64) + maxpool -----
// One wave per query. Weights for L1/L2 read straight from GLOBAL with
// wave-uniform addresses -> compiler scalarizes to s_load (scalar cache,
// co-issues with VALU; no LDS broadcast traffic). L3: LDS transpose (stride
// 36) -> lane = out channel, w3 row in regs, rows capped at valid count.
// Single wave: DS ops are in-order per wave -> no barriers at all.
__global__ __launch_bounds__(T2, 1) void group_mlp_kernel(
        const float* __restrict__ xyz,  const float* __restrict__ points,
        const float* __restrict__ w1,   const float* __restrict__ b1,
        const float* __restrict__ w2,   const float* __restrict__ b2,
        const float* __restrict__ w3,   const float* __restrict__ b3,
        const float* __restrict__ new_xyz, float* __restrict__ new_points) {
    __shared__ unsigned short sidx[NPTS];  // 4 KB
    __shared__ float sh2[64 * 36];         // 9 KB, 16B-aligned rows
    const int lane = threadIdx.x;

    float wf3[32];                         // lane's w3 row (lane = out channel)
    {
        const float4* w3v = (const float4*)(w3 + lane * 32);
#pragma unroll
        for (int j = 0; j < 8; ++j) {
            float4 v = w3v[j];
            wf3[j*4+0] = v.x; wf3[j*4+1] = v.y; wf3[j*4+2] = v.z; wf3[j*4+3] = v.w;
        }
    }
    const float rb3 = b3[lane];

    const int q = blockIdx.x;
    const int b = q >> 9;
    const int s = q & (SOUT - 1);
    const float qx = new_xyz[q*3+0], qy = new_xyz[q*3+1], qz = new_xyz[q*3+2];
    const float qs = __fadd_rn(__fadd_rn(__fmul_rn(qx,qx), __fmul_rn(qy,qy)), __fmul_rn(qz,qz));
    const float* xb = xyz    + (size_t)b * NPTS * 3;
    const float* pb = points + (size_t)b * 13 * NPTS;

    // scan all N points, ballot-compact within-radius indices (ascending)
    int cnt = 0;
    for (int r = 0; r < NPTS / T2; ++r) {
        int n = r * T2 + lane;
        float x = xb[n*3+0], y = xb[n*3+1], z = xb[n*3+2];
        float pn = __fadd_rn(__fadd_rn(__fmul_rn(x,x), __fmul_rn(y,y)), __fmul_rn(z,z));
        float dt = __fadd_rn(__fadd_rn(__fmul_rn(qx,x), __fmul_rn(qy,y)), __fmul_rn(qz,z));
        float sqr = __fsub_rn(__fadd_rn(qs, pn), __fmul_rn(2.0f, dt));
        bool sel = !(sqr > 0.04f);                    // keep iff sqr <= r^2 (f32)
        unsigned long long m = __ballot(sel);
        if (sel) sidx[cnt + __popcll(m & ((1ull << lane) - 1ull))] = (unsigned short)n;
        cnt += (int)__popcll(m);
    }
    const int K = cnt;                                 // >= 1
    const int nfirst = (int)sidx[0];

    float mx = -3.0e38f;
    for (int tb = 0; tb < K; tb += T2) {
        int m = tb + lane;
        int n = (m < K) ? (int)sidx[m] : nfirst;       // pad = first neighbor
        float f[16];
        f[0] = xb[n*3+0] - qx;
        f[1] = xb[n*3+1] - qy;
        f[2] = xb[n*3+2] - qz;
#pragma unroll
        for (int c = 0; c < 13; ++c) f[3+c] = pb[c*NPTS + n];
        float h1[32];
#pragma unroll
        for (int o = 0; o < 32; ++o) {
            float acc = b1[o];                         // uniform -> s_load
            const float4* wr = (const float4*)(w1 + o*16);   // uniform rows
#pragma unroll
            for (int c4 = 0; c4 < 4; ++c4) {
                float4 wv = wr[c4];
                acc = fmaf(f[c4*4+0], wv.x, acc);
                acc = fmaf(f[c4*4+1], wv.y, acc);
                acc = fmaf(f[c4*4+2], wv.z, acc);
                acc = fmaf(f[c4*4+3], wv.w, acc);
            }
            h1[o] = fmaxf(acc, 0.0f);
        }
        float h2[32];
#pragma unroll
        for (int o = 0; o < 32; ++o) {
            float acc = b2[o];                         // uniform -> s_load
            const float4* wr = (const float4*)(w2 + o*32);
#pragma unroll
            for (int c4 = 0; c4 < 8; ++c4) {
                float4 wv = wr[c4];
                acc = fmaf(h1[c4*4+0], wv.x, acc);
                acc = fmaf(h1[c4*4+1], wv.y, acc);
                acc = fmaf(h1[c4*4+2], wv.z, acc);
                acc = fmaf(h1[c4*4+3], wv.w, acc);
            }
            h2[o] = fmaxf(acc, 0.0f);
        }
        // stage h2 (lane = neighbor row) then lane = out channel; single wave
        // -> DS in-order, no barrier (WAR across iterations is wave-ordered)
        {
            float4* row = (float4*)(sh2 + lane * 36);
#pragma unroll
            for (int c4 = 0; c4 < 8; ++c4)
                row[c4] = make_float4(h2[c4*4+0], h2[c4*4+1], h2[c4*4+2], h2[c4*4+3]);
        }
        int rows = K - tb; if (rows > T2) rows = T2;   // cap at valid rows
#pragma unroll 4
        for (int n2 = 0; n2 < rows; ++n2) {
            const float4* hr = (const float4*)(sh2 + n2 * 36);
            float acc = rb3;
#pragma unroll
            for (int c4 = 0; c4 < 8; ++c4) {
                float4 h = hr[c4];
                acc = fmaf(h.x, wf3[c4*4+0], acc);
                acc = fmaf(h.y, wf3[c4*4+1], acc);
                acc = fmaf(h.z, wf3[c4*4+2], acc);
                acc = fmaf(h.w, wf3[c4*4+3], acc);
            }
            mx = fmaxf(mx, acc);
        }
    }
    new_points[((size_t)b * 64 + lane) * SOUT + s] = mx;   // (B, 64, S)
}

// ---------------- host: threefry2x32 (JAX key(42) randint seed) --------------
static inline uint32_t rotl32(uint32_t x, int r) { return (x << r) | (x >> (32 - r)); }
static void threefry2x32_host(uint32_t k0, uint32_t k1, uint32_t& x0, uint32_t& x1) {
    const int R[2][4] = {{13,15,26,6},{17,29,16,24}};
    uint32_t ks[3] = {k0, k1, k0 ^ k1 ^ 0x1BD11BDAu};
    x0 += ks[0]; x1 += ks[1];
    for (int i = 0; i < 5; ++i) {
        for (int j = 0; j < 4; ++j) { x0 += x1; x1 = rotl32(x1, R[i & 1][j]); x1 ^= x0; }
        x0 += ks[(i + 1) % 3];
        x1 += ks[(i + 2) % 3] + (uint32_t)(i + 1);
    }
}

extern "C" void kernel_launch(void* const* d_in, const int* in_sizes, int n_in,
                              void* d_out, int out_size, void* d_ws, size_t ws_size,
                              hipStream_t stream) {
    const float* xyz    = (const float*)d_in[0];
    const float* points = (const float*)d_in[1];
    const float* w1 = (const float*)d_in[2];
    const float* b1 = (const float*)d_in[3];
    const float* w2 = (const float*)d_in[4];
    const float* b2 = (const float*)d_in[5];
    const float* w3 = (const float*)d_in[6];
    const float* b3 = (const float*)d_in[7];
    float* out        = (float*)d_out;
    float* new_xyz    = out;                      // (B, S, 3)
    float* new_points = out + NB * SOUT * 3;      // (B, 64, S)

    // jax.random.randint(key(42), (2,), 0, 2048), modern JAX
    // (jax_threefry_partitionable=True): _randint splits the key first:
    //   k1, k2 = split(key); result = random_bits(k2, 32, (2,)) & 2047
    // foldlike split: k2 = threefry((0,42),(0,1)) full pair.
    // partitionable bits: elem i = xor-halves of threefry(k2, (0,i)).
    // (VERIFIED passing in rounds 3-5 — do not change.)
    uint32_t k2a = 0, k2b = 1; threefry2x32_host(0u, 42u, k2a, k2b);
    uint32_t u0 = 0, u1 = 0;  threefry2x32_host(k2a, k2b, u0, u1);
    uint32_t v0 = 0, v1 = 1;  threefry2x32_host(k2a, k2b, v0, v1);
    int far0 = (int)((u0 ^ u1) & (NPTS - 1));
    int far1 = (int)((v0 ^ v1) & (NPTS - 1));

    hipLaunchKernelGGL(fps_kernel, dim3(NB), dim3(T1), 0, stream,
                       xyz, new_xyz, far0, far1);
    hipLaunchKernelGGL(group_mlp_kernel, dim3(NB * SOUT), dim3(T2), 0, stream,
                       xyz, points, w1, b1, w2, b2, w3, b3, new_xyz, new_points);
}